// Round 14
// baseline (417.832 us; speedup 1.0000x reference)
//
#include <hip/hip_runtime.h>
#include <stdint.h>

typedef __bf16 bf16;
typedef __bf16 bf16x8 __attribute__((ext_vector_type(8)));
typedef float f32x4 __attribute__((ext_vector_type(4)));

__device__ __forceinline__ void gload_lds16(const void* g, void* l) {
    __builtin_amdgcn_global_load_lds(
        (const __attribute__((address_space(1))) unsigned int*)g,
        (__attribute__((address_space(3))) unsigned int*)l, 16, 0, 0);
}

#define BAR()    asm volatile("s_barrier" ::: "memory")
#define WAITV(N) asm volatile("s_waitcnt vmcnt(" #N ")" ::: "memory")

// ---- shared 8-phase machinery (identical schedule to r6..r13) ----
#define STG(S, R, G, KOFF2, RS) do { \
    const bf16* _g = (G) + (KOFF2); \
    gload_lds16(_g,      &lds[S][R][d0]); \
    gload_lds16(_g + RS, &lds[S][R][d1]); \
  } while (0)

#define RD(S, R, OFF) (*(const bf16x8*)((const char*)&lds[S][R][0] + (OFF)))

#define MM(MB) \
    __builtin_amdgcn_s_setprio(1); \
    _Pragma("unroll") for (int mi = 0; mi < 4; ++mi) \
      _Pragma("unroll") for (int nj = 0; nj < 4; ++nj) \
        acc[MB + mi][nj] = __builtin_amdgcn_mfma_f32_16x16x32_bf16(av[mi], bv[nj], acc[MB + mi][nj], 0, 0, 0); \
    __builtin_amdgcn_s_setprio(0);

#define PH1(S, STGX) { \
    _Pragma("unroll") for (int nj = 0; nj < 4; ++nj) bv[nj] = RD(S, 2, bBase + nj * 1024); \
    _Pragma("unroll") for (int mi = 0; mi < 4; ++mi) av[mi] = RD(S, 0, aBase + mi * 1024); \
    STGX; BAR(); MM(0) BAR(); }

#define PH2(S, STGX) { \
    _Pragma("unroll") for (int mi = 0; mi < 4; ++mi) av[mi] = RD(S, 0, aBase + 4096 + mi * 1024); \
    STGX; BAR(); MM(4) BAR(); }

#define PH3(S, STGX) { \
    _Pragma("unroll") for (int nj = 0; nj < 4; ++nj) bv[nj] = RD(S, 3, bBase + nj * 1024); \
    _Pragma("unroll") for (int mi = 0; mi < 4; ++mi) av[mi] = RD(S, 1, aBase + mi * 1024); \
    STGX; BAR(); MM(0) BAR(); }

#define PH4(S, STGX, WT) { \
    _Pragma("unroll") for (int mi = 0; mi < 4; ++mi) av[mi] = RD(S, 1, aBase + 4096 + mi * 1024); \
    STGX; BAR(); MM(4) WT; BAR(); }

// ============================================================================
// Fused q/k/v projections: one 1152-block dispatch (unchanged from r12/r13).
// ============================================================================
__global__ __launch_bounds__(512, 2)
void gemm_qkv(const bf16* __restrict__ Tb, const bf16* __restrict__ Sb,
              const bf16* __restrict__ Wq, const bf16* __restrict__ Wk,
              const bf16* __restrict__ Wv,
              bf16* __restrict__ Qo, bf16* __restrict__ Ko, bf16* __restrict__ VTo)
{
    __shared__ __align__(16) bf16 lds[2][4][8192];

    const int nwg  = gridDim.x;
    const int orig = blockIdx.x;
    const int q8   = nwg >> 3, r8 = nwg & 7;
    const int xcd  = orig & 7, lid = orig >> 3;
    const int p    = (xcd < r8 ? xcd * (q8 + 1) : r8 * (q8 + 1) + (xcd - r8) * q8) + lid;

    const bf16 *A, *Bw; bf16 *Co; bool vt = false;
    int lp;
    if (p < 512)       { lp = p;        A = Sb; Bw = Wk; Co = Ko; }
    else if (p < 1024) { lp = p - 512;  A = Sb; Bw = Wv; Co = VTo; vt = true; }
    else               { lp = p - 1024; A = Tb; Bw = Wq; Co = Qo; }

    const long rowb = (long)(lp >> 2) << 8;   // GC=4: 4 consecutive share A-panel
    const long colb = (long)(lp & 3) << 8;

    const int t  = threadIdx.x;
    const int l  = t & 63;
    const int w  = t >> 6;
    const int wm = w >> 2;
    const int wn = w & 3;
    const int l15 = l & 15;
    const int r0  = (l >> 4) << 2;

    const int sL   = (t * 16) ^ (((t >> 3) & 3) << 4);
    const int srow = sL >> 6;
    const int sk   = (sL & 63) >> 1;
    const bf16* gA = A + (rowb + srow) * 1024 + sk;
    const bf16* gB = Bw + (colb + srow) * 1024 + sk;
    const long rA = 131072, rB = 131072;      // 128*1024
    const int  d0 = t * 8, d1 = t * 8 + 4096;

    const int xl    = ((l >> 1) & 3) << 4;
    const int aBase = ((wm * 128 + l15) * 64 + ((l >> 4) << 4)) ^ xl;
    const int bBase = ((wn * 64  + l15) * 64 + ((l >> 4) << 4)) ^ xl;

    f32x4 acc[8][4] = {};
    bf16x8 av[4], bv[4];

    STG(0, 0, gA, 0,  rA);
    STG(0, 1, gA, 32, rA);
    STG(0, 2, gB, 0,  rB);
    STG(0, 3, gB, 32, rB);
    STG(1, 2, gB, 64, rB);
    STG(1, 0, gA, 64, rA);
    STG(1, 3, gB, 96, rB);
    WAITV(6);
    BAR();

    for (int i = 0; i < 7; ++i) {
        const int kb = i << 7;
        const int kn = kb + 128;
        PH1(0, STG(1, 1, gA, kb + 96, rA));
        PH2(0, STG(0, 2, gB, kn,      rB));
        PH3(0, STG(0, 0, gA, kn,      rA));
        PH4(0, STG(0, 3, gB, kn + 32, rB), WAITV(6));
        PH1(1, STG(0, 1, gA, kn + 32, rA));
        PH2(1, STG(1, 2, gB, kn + 64, rB));
        PH3(1, STG(1, 0, gA, kn + 64, rA));
        PH4(1, STG(1, 3, gB, kn + 96, rB), WAITV(6));
    }
    {
        PH1(0, STG(1, 1, gA, 7 * 128 + 96, rA));
        PH2(0, );
        PH3(0, );
        PH4(0, , WAITV(0));
        PH1(1, );
        PH2(1, );
        PH3(1, );
        PH4(1, , );
    }

    // LDS-staged epilogue (two 128-row halves, [128][280] bf16)
    bf16* epi = &lds[0][0][0];
    const int rrow   = t >> 5;
    const int cchunk = (t & 31) << 3;
    const int myh = vt ? (wn >> 1) : wm;
#pragma unroll
    for (int h = 0; h < 2; ++h) {
        if (myh == h) {
#pragma unroll
            for (int mf = 0; mf < 8; ++mf)
#pragma unroll
              for (int nj = 0; nj < 4; ++nj)
#pragma unroll
                for (int r = 0; r < 4; ++r) {
                    int orow = wm * 128 + mf * 16 + r0 + r;
                    int ocol = wn * 64 + nj * 16 + l15;
                    if (vt) { int tmp = orow; orow = ocol; ocol = tmp; }
                    epi[(orow - h * 128) * 280 + ocol] = (bf16)acc[mf][nj][r];
                }
        }
        __syncthreads();
#pragma unroll
        for (int pp = 0; pp < 8; ++pp) {
            const int lrow = pp * 16 + rrow;
            const int row  = h * 128 + lrow;
            uint4 d = *(const uint4*)&epi[lrow * 280 + cchunk];
            if (!vt) {
                *(uint4*)&Co[(rowb + row) * 1024 + colb + cchunk] = d;
            } else {
                const long zz  = rowb >> 12;
                const long lk0 = (rowb & 4095) + cchunk;
                *(uint4*)&Co[zz * 4194304L + (colb + row) * 4096L + lk0] = d;
            }
        }
        __syncthreads();
    }
}

// ============================================================================
// Batched 256^2 8-phase GEMM. C = alpha * A @ B^T. lda/ldb decoupled.
// OMODE: 2 = f32 row-major scatter with per-row 1/Smp[z*1024+row] scaling
//            (o-proj from unnormalized PV partials; softmax div folded here);
//        3 = PV split-K=2: bf16 partials side-by-side to
//            Cv + z*batchC + (p>>7)*1024, row stride N=2048;
//        4 = QK: bf16 exp(alpha*acc) via LDS epilogue + per-(row,col-block)
//            partial row sums to Smp[row*16 + bx].
// ============================================================================
template<int OMODE>
__global__ __launch_bounds__(512, 2)
void gemm256(const bf16* __restrict__ A, const bf16* __restrict__ B,
             void* __restrict__ Cv, int K, int N,
             long batchA, long batchB, long batchC, float alpha,
             int nbx, int nby, int GC, int lda, int ldb,
             float* __restrict__ Smp)
{
    __shared__ __align__(16) bf16 lds[2][4][8192];

    const int nwg  = gridDim.x;
    const int orig = blockIdx.x;
    const int q8   = nwg >> 3, r8 = nwg & 7;
    const int xcd  = orig & 7, lid = orig >> 3;
    int p = (xcd < r8 ? xcd * (q8 + 1) : r8 * (q8 + 1) + (xcd - r8) * q8) + lid;

    int hv = 0;
    if constexpr (OMODE == 3) { hv = p >> 7; p &= 127; }
    const int kOff = hv << 11;

    const int perb = nbx * nby;
    const int z    = p / perb;
    const int pb   = p - z * perb;
    const int sw   = nby * GC;
    const int st   = pb / sw;
    const int rem  = pb - st * sw;
    const int by   = rem / GC;
    const int bx   = st * GC + (rem - by * GC);

    const long rowb = (long)by << 8;
    const long colb = (long)bx << 8;

    const int t  = threadIdx.x;
    const int l  = t & 63;
    const int w  = t >> 6;
    const int wm = w >> 2;
    const int wn = w & 3;
    const int l15 = l & 15;
    const int r0  = (l >> 4) << 2;

    const int sL   = (t * 16) ^ (((t >> 3) & 3) << 4);
    const int srow = sL >> 6;
    const int sk   = (sL & 63) >> 1;
    const bf16* gA = A + (long)z * batchA + (rowb + srow) * (long)lda + sk + kOff;
    const bf16* gB = B + (long)z * batchB + (colb + srow) * (long)ldb + sk + kOff;
    const long rA = 128L * lda;
    const long rB = 128L * ldb;
    const int  d0 = t * 8, d1 = t * 8 + 4096;

    const int xl    = ((l >> 1) & 3) << 4;
    const int aBase = ((wm * 128 + l15) * 64 + ((l >> 4) << 4)) ^ xl;
    const int bBase = ((wn * 64  + l15) * 64 + ((l >> 4) << 4)) ^ xl;

    f32x4 acc[8][4] = {};
    bf16x8 av[4], bv[4];

    STG(0, 0, gA, 0,  rA);
    STG(0, 1, gA, 32, rA);
    STG(0, 2, gB, 0,  rB);
    STG(0, 3, gB, 32, rB);
    STG(1, 2, gB, 64, rB);
    STG(1, 0, gA, 64, rA);
    STG(1, 3, gB, 96, rB);
    WAITV(6);
    BAR();

    const int NI = K >> 7;
    for (int i = 0; i < NI - 1; ++i) {
        const int kb = i << 7;
        const int kn = kb + 128;
        PH1(0, STG(1, 1, gA, kb + 96, rA));
        PH2(0, STG(0, 2, gB, kn,      rB));
        PH3(0, STG(0, 0, gA, kn,      rA));
        PH4(0, STG(0, 3, gB, kn + 32, rB), WAITV(6));
        PH1(1, STG(0, 1, gA, kn + 32, rA));
        PH2(1, STG(1, 2, gB, kn + 64, rB));
        PH3(1, STG(1, 0, gA, kn + 64, rA));
        PH4(1, STG(1, 3, gB, kn + 96, rB), WAITV(6));
    }
    {
        const int kb = (NI - 1) << 7;
        PH1(0, STG(1, 1, gA, kb + 96, rA));
        PH2(0, );
        PH3(0, );
        PH4(0, , WAITV(0));
        PH1(1, );
        PH2(1, );
        PH3(1, );
        PH4(1, , );
    }

    if constexpr (OMODE == 2) {
        // f32 scatter with per-row softmax normalization (full 64-B lines)
        const long cb0 = colb + wn * 64 + l15;
        const long rb0 = rowb + wm * 128 + r0;
#pragma unroll
        for (int mf = 0; mf < 8; ++mf)
#pragma unroll
          for (int r = 0; r < 4; ++r) {
            const long row = rb0 + mf * 16 + r;
            const float inv = 1.f / Smp[(long)z * 1024 + row];
#pragma unroll
            for (int nj = 0; nj < 4; ++nj)
                ((float*)Cv)[(long)z * batchC + row * (long)N + cb0 + nj * 16]
                    = acc[mf][nj][r] * inv;
          }
    } else {
        // LDS-staged bf16 epilogue (OMODE 3: partials side-by-side; 4: exp+sums)
        bf16* Cb;
        if constexpr (OMODE == 3)
            Cb = (bf16*)Cv + (long)z * batchC + (long)hv * 1024;
        else
            Cb = (bf16*)Cv + (long)z * batchC;
        bf16* epi = &lds[0][0][0];
        const int rrow   = t >> 5;
        const int cchunk = (t & 31) << 3;
#pragma unroll
        for (int h = 0; h < 2; ++h) {
            if (wm == h) {
#pragma unroll
                for (int mf = 0; mf < 8; ++mf)
#pragma unroll
                  for (int nj = 0; nj < 4; ++nj)
#pragma unroll
                    for (int r = 0; r < 4; ++r) {
                        float v = acc[mf][nj][r];
                        if constexpr (OMODE == 4) v = __expf(v * alpha);
                        const int orow = wm * 128 + mf * 16 + r0 + r;
                        const int ocol = wn * 64 + nj * 16 + l15;
                        epi[(orow - h * 128) * 280 + ocol] = (bf16)v;
                    }
            }
            __syncthreads();
#pragma unroll
            for (int pp = 0; pp < 8; ++pp) {
                const int lrow = pp * 16 + rrow;
                const int row  = h * 128 + lrow;
                union { uint4 u; bf16 h8[8]; } ud;
                ud.u = *(const uint4*)&epi[lrow * 280 + cchunk];
                *(uint4*)&Cb[(rowb + row) * (long)N + colb + cchunk] = ud.u;
                if constexpr (OMODE == 4) {
                    float s = 0.f;
#pragma unroll
                    for (int j = 0; j < 8; ++j) s += (float)ud.h8[j];
                    s += __shfl_xor(s, 1);
                    s += __shfl_xor(s, 2);
                    s += __shfl_xor(s, 4);
                    s += __shfl_xor(s, 8);
                    s += __shfl_xor(s, 16);
                    if ((t & 31) == 0)
                        Smp[((long)z * 1024 + rowb + row) * 16 + (colb >> 8)] = s;
                }
            }
            __syncthreads();
        }
    }
}

#undef STG
#undef RD
#undef MM
#undef PH1
#undef PH2
#undef PH3
#undef PH4

// single fused f32->bf16 convert: T (1048576 vec8) | S (4194304) | W4 (524288)
__global__ void cvt_all(const float* __restrict__ T, const float* __restrict__ S,
                        const float* __restrict__ Wq, const float* __restrict__ Wk,
                        const float* __restrict__ Wv, const float* __restrict__ Wo,
                        bf16* __restrict__ Tb, bf16* __restrict__ Sb,
                        bf16* __restrict__ Wb)
{
    const long i = (long)blockIdx.x * 256 + threadIdx.x;
    const float* src; bf16* dst; long j;
    if (i < 1048576)              { src = T; dst = Tb; j = i; }
    else if (i < 1048576+4194304) { src = S; dst = Sb; j = i - 1048576; }
    else {
        long k = i - 5242880;
        const int seg = (int)(k >> 17);
        j = k & 131071;
        src = seg == 0 ? Wq : seg == 1 ? Wk : seg == 2 ? Wv : Wo;
        dst = Wb + (long)seg * 1048576;
    }
    const float4* pp = (const float4*)src + j * 2;
    float4 a = pp[0], b = pp[1];
    union { bf16 h[8]; uint4 u; } o;
    o.h[0] = (bf16)a.x; o.h[1] = (bf16)a.y; o.h[2] = (bf16)a.z; o.h[3] = (bf16)a.w;
    o.h[4] = (bf16)b.x; o.h[5] = (bf16)b.y; o.h[6] = (bf16)b.z; o.h[7] = (bf16)b.w;
    ((uint4*)dst)[j] = o.u;
}

// Wob2[f][0:1024] = Wob2[f][1024:2048] = Wob[f][:]  (bf16, vec8 granularity)
__global__ void dup_wo(const bf16* __restrict__ Wo1, bf16* __restrict__ Wo2)
{
    const int i  = blockIdx.x * 256 + threadIdx.x;   // 131072 vec8
    const int f  = i >> 7;
    const int e8 = (i & 127) << 3;
    uint4 d = ((const uint4*)Wo1)[i];
    *(uint4*)&Wo2[(long)f * 2048 + e8]        = d;
    *(uint4*)&Wo2[(long)f * 2048 + 1024 + e8] = d;
}

// Sm[r] = sum of Smp[r*16 .. r*16+15]; 8192 rows
__global__ __launch_bounds__(256)
void sum16(const float* __restrict__ Smp, float* __restrict__ Sm)
{
    const int r = blockIdx.x * 256 + threadIdx.x;
    const float4* p4 = (const float4*)(Smp + (long)r * 16);
    float4 a = p4[0], b = p4[1], c = p4[2], d = p4[3];
    Sm[r] = ((a.x + a.y) + (a.z + a.w)) + ((b.x + b.y) + (b.z + b.w))
          + ((c.x + c.y) + (c.z + c.w)) + ((d.x + d.y) + (d.z + d.w));
}

extern "C" void kernel_launch(void* const* d_in, const int* in_sizes, int n_in,
                              void* d_out, int out_size, void* d_ws, size_t ws_size,
                              hipStream_t stream)
{
    (void)in_sizes; (void)n_in; (void)out_size; (void)ws_size;
    const float* T  = (const float*)d_in[0];
    const float* S  = (const float*)d_in[1];
    const float* Wq = (const float*)d_in[2];
    const float* Wk = (const float*)d_in[3];
    const float* Wv = (const float*)d_in[4];
    const float* Wo = (const float*)d_in[5];
    float* Y = (float*)d_out;
    char* ws = (char*)d_ws;

    bf16* Wqb = (bf16*)(ws + 0);           // 4 weights contiguous, 8MB
    bf16* Wkb = (bf16*)(ws + 2097152);
    bf16* Wvb = (bf16*)(ws + 4194304);
    bf16* Wob = (bf16*)(ws + 6291456);
    bf16* Tb  = (bf16*)(ws + 8388608);     // 16MB
    bf16* Qb  = (bf16*)(ws + 25165824);    // 16MB; reused as Wob2 after QK
    bf16* Wob2= Qb;                        //   [1024][2048] = 4MB
    bf16* Sb  = (bf16*)(ws + 41943040);    // 64MB; reused as P(=expS)
    bf16* Pb  = Sb;
    bf16* Kb  = (bf16*)(ws + 109051904);   // 64MB; reused as PV partials
    bf16* Pt  = Kb;                        //   [8][1024][2048] bf16 = 32MB
    bf16* VTb = (bf16*)(ws + 176160768);   // 64MB
    float* Sm  = (float*)ws;               // row sums (Wqb region, dead post-qkv)
    float* Smp = (float*)(ws + 2097152);   // partials [8192][16] (Wkb region)

    // single fused convert dispatch
    cvt_all<<<22528, 256, 0, stream>>>(T, S, Wq, Wk, Wv, Wo, Tb, Sb, Wqb);

    // fused q/k/v projections (1152 blocks)
    gemm_qkv<<<1152, 512, 0, stream>>>(Tb, Sb, Wqb, Wkb, Wvb, Qb, Kb, VTb);

    // expS = exp((q k^T)*D^-0.5), with fused per-block row-sum partials
    gemm256<4><<<512, 512, 0, stream>>>(Qb, Kb, Pb, 1024, 4096,
        1024L * 1024, 4096L * 1024, 1024L * 4096, 0.03125f, 16, 4, 4, 1024, 1024, Smp);

    // Sm[8192] = sum of 16 col-block partials per row; Wob2 = [Wo|Wo]
    sum16 <<<32,  256, 0, stream>>>(Smp, Sm);
    dup_wo<<<512, 256, 0, stream>>>(Wob, Wob2);

    // O' = expS V : split-K=2, 256 blocks, bf16 partials side-by-side -> Pt
    gemm256<3><<<256, 512, 0, stream>>>(Pb, VTb, Pt, 2048, 2048,
        1024L * 4096, 1024L * 4096, 2097152, 1.f, 4, 4, 4, 4096, 4096, nullptr);

    // Y = (1/s) * [Pt0|Pt1] @ [Wo|Wo]^T  (K=2048; softmax div in epilogue)
    gemm256<2><<<128, 512, 0, stream>>>(Pt, Wob2, Y, 2048, 1024,
        2097152, 0, 1048576, 1.f, 4, 4, 4, 2048, 2048, Sm);
}

// Round 15
// 399.790 us; speedup vs baseline: 1.0451x; 1.0451x over previous
//
#include <hip/hip_runtime.h>
#include <stdint.h>

typedef __bf16 bf16;
typedef __bf16 bf16x8 __attribute__((ext_vector_type(8)));
typedef float f32x4 __attribute__((ext_vector_type(4)));

__device__ __forceinline__ void gload_lds16(const void* g, void* l) {
    __builtin_amdgcn_global_load_lds(
        (const __attribute__((address_space(1))) unsigned int*)g,
        (__attribute__((address_space(3))) unsigned int*)l, 16, 0, 0);
}

#define BAR()    asm volatile("s_barrier" ::: "memory")
#define WAITV(N) asm volatile("s_waitcnt vmcnt(" #N ")" ::: "memory")

// ---- shared 8-phase machinery (identical schedule to r6/r9/r11/r12) ----
#define STG(S, R, G, KOFF2, RS) do { \
    const bf16* _g = (G) + (KOFF2); \
    gload_lds16(_g,      &lds[S][R][d0]); \
    gload_lds16(_g + RS, &lds[S][R][d1]); \
  } while (0)

#define RD(S, R, OFF) (*(const bf16x8*)((const char*)&lds[S][R][0] + (OFF)))

#define MM(MB) \
    __builtin_amdgcn_s_setprio(1); \
    _Pragma("unroll") for (int mi = 0; mi < 4; ++mi) \
      _Pragma("unroll") for (int nj = 0; nj < 4; ++nj) \
        acc[MB + mi][nj] = __builtin_amdgcn_mfma_f32_16x16x32_bf16(av[mi], bv[nj], acc[MB + mi][nj], 0, 0, 0); \
    __builtin_amdgcn_s_setprio(0);

#define PH1(S, STGX) { \
    _Pragma("unroll") for (int nj = 0; nj < 4; ++nj) bv[nj] = RD(S, 2, bBase + nj * 1024); \
    _Pragma("unroll") for (int mi = 0; mi < 4; ++mi) av[mi] = RD(S, 0, aBase + mi * 1024); \
    STGX; BAR(); MM(0) BAR(); }

#define PH2(S, STGX) { \
    _Pragma("unroll") for (int mi = 0; mi < 4; ++mi) av[mi] = RD(S, 0, aBase + 4096 + mi * 1024); \
    STGX; BAR(); MM(4) BAR(); }

#define PH3(S, STGX) { \
    _Pragma("unroll") for (int nj = 0; nj < 4; ++nj) bv[nj] = RD(S, 3, bBase + nj * 1024); \
    _Pragma("unroll") for (int mi = 0; mi < 4; ++mi) av[mi] = RD(S, 1, aBase + mi * 1024); \
    STGX; BAR(); MM(0) BAR(); }

#define PH4(S, STGX, WT) { \
    _Pragma("unroll") for (int mi = 0; mi < 4; ++mi) av[mi] = RD(S, 1, aBase + 4096 + mi * 1024); \
    STGX; BAR(); MM(4) WT; BAR(); }

// ============================================================================
// Fused q/k/v projections: one 1152-block dispatch.
// ============================================================================
__global__ __launch_bounds__(512, 2)
void gemm_qkv(const bf16* __restrict__ Tb, const bf16* __restrict__ Sb,
              const bf16* __restrict__ Wq, const bf16* __restrict__ Wk,
              const bf16* __restrict__ Wv,
              bf16* __restrict__ Qo, bf16* __restrict__ Ko, bf16* __restrict__ VTo)
{
    __shared__ __align__(16) bf16 lds[2][4][8192];

    const int nwg  = gridDim.x;
    const int orig = blockIdx.x;
    const int q8   = nwg >> 3, r8 = nwg & 7;
    const int xcd  = orig & 7, lid = orig >> 3;
    const int p    = (xcd < r8 ? xcd * (q8 + 1) : r8 * (q8 + 1) + (xcd - r8) * q8) + lid;

    const bf16 *A, *Bw; bf16 *Co; bool vt = false;
    int lp;
    if (p < 512)       { lp = p;        A = Sb; Bw = Wk; Co = Ko; }
    else if (p < 1024) { lp = p - 512;  A = Sb; Bw = Wv; Co = VTo; vt = true; }
    else               { lp = p - 1024; A = Tb; Bw = Wq; Co = Qo; }

    const long rowb = (long)(lp >> 2) << 8;   // GC=4: 4 consecutive share A-panel
    const long colb = (long)(lp & 3) << 8;

    const int t  = threadIdx.x;
    const int l  = t & 63;
    const int w  = t >> 6;
    const int wm = w >> 2;
    const int wn = w & 3;
    const int l15 = l & 15;
    const int r0  = (l >> 4) << 2;

    const int sL   = (t * 16) ^ (((t >> 3) & 3) << 4);
    const int srow = sL >> 6;
    const int sk   = (sL & 63) >> 1;
    const bf16* gA = A + (rowb + srow) * 1024 + sk;
    const bf16* gB = Bw + (colb + srow) * 1024 + sk;
    const long rA = 131072, rB = 131072;      // 128*1024
    const int  d0 = t * 8, d1 = t * 8 + 4096;

    const int xl    = ((l >> 1) & 3) << 4;
    const int aBase = ((wm * 128 + l15) * 64 + ((l >> 4) << 4)) ^ xl;
    const int bBase = ((wn * 64  + l15) * 64 + ((l >> 4) << 4)) ^ xl;

    f32x4 acc[8][4] = {};
    bf16x8 av[4], bv[4];

    STG(0, 0, gA, 0,  rA);
    STG(0, 1, gA, 32, rA);
    STG(0, 2, gB, 0,  rB);
    STG(0, 3, gB, 32, rB);
    STG(1, 2, gB, 64, rB);
    STG(1, 0, gA, 64, rA);
    STG(1, 3, gB, 96, rB);
    WAITV(6);
    BAR();

    for (int i = 0; i < 7; ++i) {
        const int kb = i << 7;
        const int kn = kb + 128;
        PH1(0, STG(1, 1, gA, kb + 96, rA));
        PH2(0, STG(0, 2, gB, kn,      rB));
        PH3(0, STG(0, 0, gA, kn,      rA));
        PH4(0, STG(0, 3, gB, kn + 32, rB), WAITV(6));
        PH1(1, STG(0, 1, gA, kn + 32, rA));
        PH2(1, STG(1, 2, gB, kn + 64, rB));
        PH3(1, STG(1, 0, gA, kn + 64, rA));
        PH4(1, STG(1, 3, gB, kn + 96, rB), WAITV(6));
    }
    {
        PH1(0, STG(1, 1, gA, 7 * 128 + 96, rA));
        PH2(0, );
        PH3(0, );
        PH4(0, , WAITV(0));
        PH1(1, );
        PH2(1, );
        PH3(1, );
        PH4(1, , );
    }

    // LDS-staged epilogue (two 128-row halves, [128][280] bf16)
    bf16* epi = &lds[0][0][0];
    const int rrow   = t >> 5;
    const int cchunk = (t & 31) << 3;
    const int myh = vt ? (wn >> 1) : wm;
#pragma unroll
    for (int h = 0; h < 2; ++h) {
        if (myh == h) {
#pragma unroll
            for (int mf = 0; mf < 8; ++mf)
#pragma unroll
              for (int nj = 0; nj < 4; ++nj)
#pragma unroll
                for (int r = 0; r < 4; ++r) {
                    int orow = wm * 128 + mf * 16 + r0 + r;
                    int ocol = wn * 64 + nj * 16 + l15;
                    if (vt) { int tmp = orow; orow = ocol; ocol = tmp; }
                    epi[(orow - h * 128) * 280 + ocol] = (bf16)acc[mf][nj][r];
                }
        }
        __syncthreads();
#pragma unroll
        for (int pp = 0; pp < 8; ++pp) {
            const int lrow = pp * 16 + rrow;
            const int row  = h * 128 + lrow;
            uint4 d = *(const uint4*)&epi[lrow * 280 + cchunk];
            if (!vt) {
                *(uint4*)&Co[(rowb + row) * 1024 + colb + cchunk] = d;
            } else {
                const long zz  = rowb >> 12;
                const long lk0 = (rowb & 4095) + cchunk;
                *(uint4*)&Co[zz * 4194304L + (colb + row) * 4096L + lk0] = d;
            }
        }
        __syncthreads();
    }
}

// ============================================================================
// Batched 256^2 8-phase GEMM. C = alpha * A @ B^T. lda/ldb decoupled.
// OMODE: 2 = f32 row-major scatter (o-proj);
//        3 = PV split-K=2: bf16 partials via LDS epilogue to
//            Cv + (p>>7)*8388608 + z*1048576 (row-major 1024 cols);
//        4 = QK: bf16 exp(alpha*acc) via LDS epilogue + per-(row,col-block)
//            partial row sums to Smp[row*16 + bx].
// ============================================================================
template<int OMODE>
__global__ __launch_bounds__(512, 2)
void gemm256(const bf16* __restrict__ A, const bf16* __restrict__ B,
             void* __restrict__ Cv, int K, int N,
             long batchA, long batchB, long batchC, float alpha,
             int nbx, int nby, int GC, int lda, int ldb,
             float* __restrict__ Smp)
{
    __shared__ __align__(16) bf16 lds[2][4][8192];

    const int nwg  = gridDim.x;
    const int orig = blockIdx.x;
    const int q8   = nwg >> 3, r8 = nwg & 7;
    const int xcd  = orig & 7, lid = orig >> 3;
    int p = (xcd < r8 ? xcd * (q8 + 1) : r8 * (q8 + 1) + (xcd - r8) * q8) + lid;

    int hv = 0;
    if constexpr (OMODE == 3) { hv = p >> 7; p &= 127; }
    const int kOff = hv << 11;

    const int perb = nbx * nby;
    const int z    = p / perb;
    const int pb   = p - z * perb;
    const int sw   = nby * GC;
    const int st   = pb / sw;
    const int rem  = pb - st * sw;
    const int by   = rem / GC;
    const int bx   = st * GC + (rem - by * GC);

    const long rowb = (long)by << 8;
    const long colb = (long)bx << 8;

    const int t  = threadIdx.x;
    const int l  = t & 63;
    const int w  = t >> 6;
    const int wm = w >> 2;
    const int wn = w & 3;
    const int l15 = l & 15;
    const int r0  = (l >> 4) << 2;

    const int sL   = (t * 16) ^ (((t >> 3) & 3) << 4);
    const int srow = sL >> 6;
    const int sk   = (sL & 63) >> 1;
    const bf16* gA = A + (long)z * batchA + (rowb + srow) * (long)lda + sk + kOff;
    const bf16* gB = B + (long)z * batchB + (colb + srow) * (long)ldb + sk + kOff;
    const long rA = 128L * lda;
    const long rB = 128L * ldb;
    const int  d0 = t * 8, d1 = t * 8 + 4096;

    const int xl    = ((l >> 1) & 3) << 4;
    const int aBase = ((wm * 128 + l15) * 64 + ((l >> 4) << 4)) ^ xl;
    const int bBase = ((wn * 64  + l15) * 64 + ((l >> 4) << 4)) ^ xl;

    f32x4 acc[8][4] = {};
    bf16x8 av[4], bv[4];

    STG(0, 0, gA, 0,  rA);
    STG(0, 1, gA, 32, rA);
    STG(0, 2, gB, 0,  rB);
    STG(0, 3, gB, 32, rB);
    STG(1, 2, gB, 64, rB);
    STG(1, 0, gA, 64, rA);
    STG(1, 3, gB, 96, rB);
    WAITV(6);
    BAR();

    const int NI = K >> 7;
    for (int i = 0; i < NI - 1; ++i) {
        const int kb = i << 7;
        const int kn = kb + 128;
        PH1(0, STG(1, 1, gA, kb + 96, rA));
        PH2(0, STG(0, 2, gB, kn,      rB));
        PH3(0, STG(0, 0, gA, kn,      rA));
        PH4(0, STG(0, 3, gB, kn + 32, rB), WAITV(6));
        PH1(1, STG(0, 1, gA, kn + 32, rA));
        PH2(1, STG(1, 2, gB, kn + 64, rB));
        PH3(1, STG(1, 0, gA, kn + 64, rA));
        PH4(1, STG(1, 3, gB, kn + 96, rB), WAITV(6));
    }
    {
        const int kb = (NI - 1) << 7;
        PH1(0, STG(1, 1, gA, kb + 96, rA));
        PH2(0, );
        PH3(0, );
        PH4(0, , WAITV(0));
        PH1(1, );
        PH2(1, );
        PH3(1, );
        PH4(1, , );
    }

    if constexpr (OMODE == 2) {
        // f32 scatter (o-proj): 16 lanes x 4B = full 64-B lines
        const long cb0 = colb + wn * 64 + l15;
        const long rb0 = rowb + wm * 128 + r0;
#pragma unroll
        for (int mf = 0; mf < 8; ++mf)
#pragma unroll
          for (int nj = 0; nj < 4; ++nj) {
            const long col = cb0 + nj * 16;
#pragma unroll
            for (int r = 0; r < 4; ++r)
                ((float*)Cv)[(long)z * batchC + (rb0 + mf * 16 + r) * (long)N + col]
                    = acc[mf][nj][r] * alpha;
          }
    } else {
        // LDS-staged bf16 epilogue (OMODE 3: plain partials; OMODE 4: exp+sums)
        bf16* Cb;
        if constexpr (OMODE == 3)
            Cb = (bf16*)Cv + (long)hv * 8388608 + (long)z * 1048576;
        else
            Cb = (bf16*)Cv + (long)z * batchC;
        bf16* epi = &lds[0][0][0];
        const int rrow   = t >> 5;
        const int cchunk = (t & 31) << 3;
#pragma unroll
        for (int h = 0; h < 2; ++h) {
            if (wm == h) {
#pragma unroll
                for (int mf = 0; mf < 8; ++mf)
#pragma unroll
                  for (int nj = 0; nj < 4; ++nj)
#pragma unroll
                    for (int r = 0; r < 4; ++r) {
                        float v = acc[mf][nj][r];
                        if constexpr (OMODE == 4) v = __expf(v * alpha);
                        const int orow = wm * 128 + mf * 16 + r0 + r;
                        const int ocol = wn * 64 + nj * 16 + l15;
                        epi[(orow - h * 128) * 280 + ocol] = (bf16)v;
                    }
            }
            __syncthreads();
#pragma unroll
            for (int pp = 0; pp < 8; ++pp) {
                const int lrow = pp * 16 + rrow;
                const int row  = h * 128 + lrow;
                union { uint4 u; bf16 h8[8]; } ud;
                ud.u = *(const uint4*)&epi[lrow * 280 + cchunk];
                *(uint4*)&Cb[(rowb + row) * (long)N + colb + cchunk] = ud.u;
                if constexpr (OMODE == 4) {
                    float s = 0.f;
#pragma unroll
                    for (int j = 0; j < 8; ++j) s += (float)ud.h8[j];
                    s += __shfl_xor(s, 1);
                    s += __shfl_xor(s, 2);
                    s += __shfl_xor(s, 4);
                    s += __shfl_xor(s, 8);
                    s += __shfl_xor(s, 16);
                    if ((t & 31) == 0)
                        Smp[((long)z * 1024 + rowb + row) * 16 + (colb >> 8)] = s;
                }
            }
            __syncthreads();
        }
    }
}

#undef STG
#undef RD
#undef MM
#undef PH1
#undef PH2
#undef PH3
#undef PH4

// single fused f32->bf16 convert: T (1048576 vec8) | S (4194304) | W4 (524288)
__global__ void cvt_all(const float* __restrict__ T, const float* __restrict__ S,
                        const float* __restrict__ Wq, const float* __restrict__ Wk,
                        const float* __restrict__ Wv, const float* __restrict__ Wo,
                        bf16* __restrict__ Tb, bf16* __restrict__ Sb,
                        bf16* __restrict__ Wb)
{
    const long i = (long)blockIdx.x * 256 + threadIdx.x;
    const float* src; bf16* dst; long j;
    if (i < 1048576)              { src = T; dst = Tb; j = i; }
    else if (i < 1048576+4194304) { src = S; dst = Sb; j = i - 1048576; }
    else {
        long k = i - 5242880;
        const int seg = (int)(k >> 17);
        j = k & 131071;
        src = seg == 0 ? Wq : seg == 1 ? Wk : seg == 2 ? Wv : Wo;
        dst = Wb + (long)seg * 1048576;
    }
    const float4* pp = (const float4*)src + j * 2;
    float4 a = pp[0], b = pp[1];
    union { bf16 h[8]; uint4 u; } o;
    o.h[0] = (bf16)a.x; o.h[1] = (bf16)a.y; o.h[2] = (bf16)a.z; o.h[3] = (bf16)a.w;
    o.h[4] = (bf16)b.x; o.h[5] = (bf16)b.y; o.h[6] = (bf16)b.z; o.h[7] = (bf16)b.w;
    ((uint4*)dst)[j] = o.u;
}

// Sm[r] = sum of Smp[r*16 .. r*16+15]; 8192 rows
__global__ __launch_bounds__(256)
void sum16(const float* __restrict__ Smp, float* __restrict__ Sm)
{
    const int r = blockIdx.x * 256 + threadIdx.x;
    const float4* p4 = (const float4*)(Smp + (long)r * 16);
    float4 a = p4[0], b = p4[1], c = p4[2], d = p4[3];
    Sm[r] = ((a.x + a.y) + (a.z + a.w)) + ((b.x + b.y) + (b.z + b.w))
          + ((c.x + c.y) + (c.z + c.w)) + ((d.x + d.y) + (d.z + d.w));
}

// Ob = bf16((Pt0 + Pt1) / s[row]); bf16 partials; 8/thread; row = i>>7
__global__ void reduce_pv(const bf16* __restrict__ Pt, const float* __restrict__ sums,
                          bf16* __restrict__ Ob)
{
    const long i = (long)blockIdx.x * 256 + threadIdx.x;
    const float inv = 1.f / sums[i >> 7];
    union U { uint4 u; bf16 h[8]; };
    U a, b, o;
    a.u = ((const uint4*)Pt)[i];
    b.u = ((const uint4*)(Pt + 8388608))[i];
#pragma unroll
    for (int j = 0; j < 8; ++j)
        o.h[j] = (bf16)(((float)a.h[j] + (float)b.h[j]) * inv);
    ((uint4*)Ob)[i] = o.u;
}

extern "C" void kernel_launch(void* const* d_in, const int* in_sizes, int n_in,
                              void* d_out, int out_size, void* d_ws, size_t ws_size,
                              hipStream_t stream)
{
    (void)in_sizes; (void)n_in; (void)out_size; (void)ws_size;
    const float* T  = (const float*)d_in[0];
    const float* S  = (const float*)d_in[1];
    const float* Wq = (const float*)d_in[2];
    const float* Wk = (const float*)d_in[3];
    const float* Wv = (const float*)d_in[4];
    const float* Wo = (const float*)d_in[5];
    float* Y = (float*)d_out;
    char* ws = (char*)d_ws;

    bf16* Wqb = (bf16*)(ws + 0);           // 4 weights contiguous, 8MB
    bf16* Wkb = (bf16*)(ws + 2097152);
    bf16* Wvb = (bf16*)(ws + 4194304);
    bf16* Wob = (bf16*)(ws + 6291456);
    bf16* Tb  = (bf16*)(ws + 8388608);     // 16MB; reused as O
    bf16* Ob  = Tb;
    bf16* Qb  = (bf16*)(ws + 25165824);    // 16MB
    bf16* Sb  = (bf16*)(ws + 41943040);    // 64MB; reused as P(=expS)
    bf16* Pb  = Sb;
    bf16* Kb  = (bf16*)(ws + 109051904);   // 64MB; reused as bf16 PV partials
    bf16* Pt  = Kb;
    bf16* VTb = (bf16*)(ws + 176160768);   // 64MB
    float* Sm  = (float*)ws;               // row sums (Wqb region, dead post-qkv)
    float* Smp = (float*)(ws + 2097152);   // partials [8192][16] (Wkb region)

    // single fused convert dispatch
    cvt_all<<<22528, 256, 0, stream>>>(T, S, Wq, Wk, Wv, Wo, Tb, Sb, Wqb);

    // fused q/k/v projections (1152 blocks)
    gemm_qkv<<<1152, 512, 0, stream>>>(Tb, Sb, Wqb, Wkb, Wvb, Qb, Kb, VTb);

    // expS = exp((q k^T)*D^-0.5), with fused per-block row-sum partials
    gemm256<4><<<512, 512, 0, stream>>>(Qb, Kb, Pb, 1024, 4096,
        1024L * 1024, 4096L * 1024, 1024L * 4096, 0.03125f, 16, 4, 4, 1024, 1024, Smp);

    // Sm[8192] = sum of 16 col-block partials per row
    sum16<<<32, 256, 0, stream>>>(Smp, Sm);

    // O' = expS V : split-K=2, 256 blocks, bf16 partials -> Pt
    gemm256<3><<<256, 512, 0, stream>>>(Pb, VTb, Pt, 2048, 1024,
        1024L * 4096, 1024L * 4096, 1048576, 1.f, 4, 4, 4, 4096, 4096, nullptr);
    // O = (Pt0+Pt1)/s  (softmax division folded in)
    reduce_pv<<<4096, 256, 0, stream>>>(Pt, Sm, Ob);

    // Y = O Wo^T (fp32 out)
    gemm256<2><<<128, 512, 0, stream>>>(Ob, Wob, Y, 1024, 1024,
        0, 0, 0, 1.f, 4, 32, 4, 1024, 1024, nullptr);
}